// Round 2
// baseline (5178.315 us; speedup 1.0000x reference)
//
#include <hip/hip_runtime.h>
#include <hip/hip_bf16.h>
#include <stdint.h>

#define T_STEPS 1024
#define NH1 1024
#define NH2 512
#define D_IN 300
#define W1_LD 1324
#define W2_LD 1536
#define NVG 50000
#define NVS 25000

typedef unsigned long long u64;
typedef __bf16 bf16x8 __attribute__((ext_vector_type(8)));
typedef short s16x8 __attribute__((ext_vector_type(8)));
typedef float f32x4 __attribute__((ext_vector_type(4)));

// ---------------------------------------------------------------------------
// Kernel 1: E[t][r] = b1[r] + sum_c W1[r][c] * X[idx[t]][c]   (c < 300)
// grid: 8 row-blocks x 32 t-blocks = 256 blocks, 256 threads. All fp32.
// ---------------------------------------------------------------------------
__global__ __launch_bounds__(256) void e_kernel(
    const float* __restrict__ X,
    const float* __restrict__ W1,
    const float* __restrict__ b1,
    const int* __restrict__ idx,
    float* __restrict__ E)
{
  __shared__ float Xs[32 * 300];
  const int rb = blockIdx.x & 7;
  const int tb = blockIdx.x >> 3;
  const int r0 = rb * 128;
  const int t0 = tb * 32;

  for (int t = 0; t < 32; ++t) {
    int node = idx[t0 + t];
    for (int c = threadIdx.x; c < 300; c += 256)
      Xs[t * 300 + c] = X[(size_t)node * D_IN + c];
  }
  __syncthreads();

  const int rl = threadIdx.x & 127;
  const int th = threadIdx.x >> 7;      // 0..1
  const int tbase = th * 16;
  const int r = r0 + rl;

  float acc[16];
  const float bias = b1[r];
#pragma unroll
  for (int tt = 0; tt < 16; ++tt) acc[tt] = bias;

  const float* wrow = W1 + (size_t)r * W1_LD;
  for (int c0 = 0; c0 < 300; c0 += 4) {
    float w0 = wrow[c0 + 0];
    float w1 = wrow[c0 + 1];
    float w2 = wrow[c0 + 2];
    float w3 = wrow[c0 + 3];
#pragma unroll
    for (int tt = 0; tt < 16; ++tt) {
      const float* xr = Xs + (tbase + tt) * 300 + c0;
      acc[tt] += w0 * xr[0] + w1 * xr[1] + w2 * xr[2] + w3 * xr[3];
    }
  }
#pragma unroll
  for (int tt = 0; tt < 16; ++tt)
    E[(size_t)(t0 + tbase + tt) * NH1 + r] = acc[tt];
}

// ---------------------------------------------------------------------------
// Kernel 2: persistent RNN. 64 blocks x 256 threads = 256 waves.
// Wave W owns h1 rows [4W,4W+4) and h2 rows [2W,2W+2); fp32 weight slice in
// VGPRs. Sync: (tag,value) packed 8B atoms in mod-4 rotating buffers; readers
// spin on the data itself. Poison 0xAAAAAAAA never matches a tag (1..1025).
// Iteration s (0..T): compute h1(s+1) [if s<T] and h2(s) [if s>=1].
// h2s written as bf16 (GEMM A-operand).
// ---------------------------------------------------------------------------
__global__ __launch_bounds__(256, 1) void rnn_kernel(
    const float* __restrict__ W1,
    const float* __restrict__ W2,
    const float* __restrict__ b2,
    const float* __restrict__ E,
    u64* __restrict__ buf1,     // [4][1024]
    u64* __restrict__ buf2,     // [4][512]
    __hip_bfloat16* __restrict__ h2s)   // [T][512]
{
  const int lane = threadIdx.x & 63;
  const int wvid = blockIdx.x * 4 + (threadIdx.x >> 6);  // 0..255
  const int r1 = wvid * 4;
  const int r2 = wvid * 2;

  float w1r[4][16];
#pragma unroll
  for (int i = 0; i < 4; ++i)
#pragma unroll
    for (int j = 0; j < 16; ++j)
      w1r[i][j] = W1[(size_t)(r1 + i) * W1_LD + D_IN + lane + 64 * j];

  float w2r[2][24];
#pragma unroll
  for (int i = 0; i < 2; ++i)
#pragma unroll
    for (int j = 0; j < 24; ++j)
      w2r[i][j] = W2[(size_t)(r2 + i) * W2_LD + lane + 64 * j];

  const float b2a = b2[r2];
  const float b2b = b2[r2 + 1];

  for (int s = 0; s <= T_STEPS; ++s) {
    float ev = 0.f;
    if (s < T_STEPS) ev = E[(size_t)s * NH1 + r1 + (lane & 3)];

    float hv1[16], hv2[8];
#pragma unroll
    for (int j = 0; j < 16; ++j) hv1[j] = 0.f;
#pragma unroll
    for (int j = 0; j < 8; ++j) hv2[j] = 0.f;

    unsigned miss1 = (s >= 1) ? 0xFFFFu : 0u;   // h1(s); s==0 -> zeros
    unsigned miss2 = (s >= 2) ? 0xFFu : 0u;     // h2(s-1); s<=1 -> zeros
    const u64* p1 = buf1 + (size_t)(s & 3) * NH1;
    const u64* p2 = buf2 + (size_t)((s - 1) & 3) * NH2;
    const unsigned tag1 = (unsigned)s;
    const unsigned tag2 = (unsigned)(s - 1);

    while (miss1 | miss2) {
      u64 t1[16], t2[8];
#pragma unroll
      for (int j = 0; j < 16; ++j)
        if (miss1 & (1u << j))
          t1[j] = __hip_atomic_load(p1 + lane + 64 * j, __ATOMIC_RELAXED,
                                    __HIP_MEMORY_SCOPE_AGENT);
#pragma unroll
      for (int j = 0; j < 8; ++j)
        if (miss2 & (1u << j))
          t2[j] = __hip_atomic_load(p2 + lane + 64 * j, __ATOMIC_RELAXED,
                                    __HIP_MEMORY_SCOPE_AGENT);
#pragma unroll
      for (int j = 0; j < 16; ++j)
        if ((miss1 & (1u << j)) && (unsigned)(t1[j] >> 32) == tag1) {
          hv1[j] = __uint_as_float((unsigned)t1[j]);
          miss1 &= ~(1u << j);
        }
#pragma unroll
      for (int j = 0; j < 8; ++j)
        if ((miss2 & (1u << j)) && (unsigned)(t2[j] >> 32) == tag2) {
          hv2[j] = __uint_as_float((unsigned)t2[j]);
          miss2 &= ~(1u << j);
        }
    }

    float a0 = 0.f, a1 = 0.f, a2 = 0.f, a3 = 0.f, a4 = 0.f, a5 = 0.f;
    if (s < T_STEPS) {
#pragma unroll
      for (int j = 0; j < 16; ++j) {
        a0 += w1r[0][j] * hv1[j];
        a1 += w1r[1][j] * hv1[j];
        a2 += w1r[2][j] * hv1[j];
        a3 += w1r[3][j] * hv1[j];
      }
    }
    if (s >= 1) {
#pragma unroll
      for (int j = 0; j < 16; ++j) {
        a4 += w2r[0][j] * hv1[j];
        a5 += w2r[1][j] * hv1[j];
      }
#pragma unroll
      for (int j = 0; j < 8; ++j) {
        a4 += w2r[0][16 + j] * hv2[j];
        a5 += w2r[1][16 + j] * hv2[j];
      }
    }

#pragma unroll
    for (int off = 32; off; off >>= 1) {
      a0 += __shfl_xor(a0, off);
      a1 += __shfl_xor(a1, off);
      a2 += __shfl_xor(a2, off);
      a3 += __shfl_xor(a3, off);
      a4 += __shfl_xor(a4, off);
      a5 += __shfl_xor(a5, off);
    }

    if (lane < 4) {
      if (s < T_STEPS) {
        float x = (lane == 0 ? a0 : lane == 1 ? a1 : lane == 2 ? a2 : a3) + ev;
        float h = x > 0.f ? x : 0.01f * x;
        u64 pk = ((u64)(unsigned)(s + 1) << 32) | (u64)__float_as_uint(h);
        __hip_atomic_store(buf1 + (size_t)((s + 1) & 3) * NH1 + r1 + lane, pk,
                           __ATOMIC_RELAXED, __HIP_MEMORY_SCOPE_AGENT);
      }
    } else if (lane < 6 && s >= 1) {
      int i = lane - 4;
      float x = (i == 0 ? a4 : a5) + (i == 0 ? b2a : b2b);
      float h = x > 0.f ? x : 0.01f * x;
      u64 pk = ((u64)(unsigned)s << 32) | (u64)__float_as_uint(h);
      __hip_atomic_store(buf2 + (size_t)(s & 3) * NH2 + r2 + i, pk,
                         __ATOMIC_RELAXED, __HIP_MEMORY_SCOPE_AGENT);
      h2s[(size_t)(s - 1) * NH2 + r2 + i] = __float2bfloat16(h);
    }
  }
}

// ---------------------------------------------------------------------------
// Kernel 3: C[m][n] = sum_k A[m][k]*B[n][k] + bias[n]  (fp32 logits out).
// A = h2s [1024][512] bf16. B = W [N][512] fp32, converted to bf16 while
// staging to LDS. 256x128x64 tiles, XOR-swizzled LDS, bf16 MFMA.
// ---------------------------------------------------------------------------
__global__ __launch_bounds__(256, 1) void gemm_kernel(
    const __hip_bfloat16* __restrict__ A,
    const float* __restrict__ B,
    const float* __restrict__ bias,
    float* __restrict__ C,
    int N)
{
  __shared__ short As[256 * 64];
  __shared__ short Bs[128 * 64];
  const int tid = threadIdx.x;
  const int lane = tid & 63;
  const int wv = tid >> 6;
  const int wm = (wv & 1) * 128;
  const int wn = (wv >> 1) * 64;
  const int m0 = blockIdx.x * 256;
  const int n0 = blockIdx.y * 128;
  const int ml = lane & 15;
  const int kq = lane >> 4;

  f32x4 acc[8][4];
#pragma unroll
  for (int i = 0; i < 8; ++i)
#pragma unroll
    for (int j = 0; j < 4; ++j)
      acc[i][j] = (f32x4){0.f, 0.f, 0.f, 0.f};

  for (int kb = 0; kb < 512; kb += 64) {
    __syncthreads();
    // A: 256 rows x 8 chunks (8 bf16 each) = 2048 chunks, 8 per thread.
#pragma unroll
    for (int q = 0; q < 8; ++q) {
      int ch = q * 256 + tid;
      int row = ch >> 3;
      int kc = ch & 7;
      int phys = kc ^ (row & 7);
      s16x8 av = *(const s16x8*)((const short*)A + (size_t)(m0 + row) * 512 + kb + kc * 8);
      *(s16x8*)(As + row * 64 + phys * 8) = av;
    }
    // B: 128 rows x 8 chunks = 1024 chunks, 4 per thread; fp32 -> bf16.
#pragma unroll
    for (int q = 0; q < 4; ++q) {
      int ch = q * 256 + tid;
      int row = ch >> 3;
      int kc = ch & 7;
      int phys = kc ^ (row & 7);
      int gr = n0 + row;
      if (gr >= N) gr = N - 1;
      const float* src = B + (size_t)gr * 512 + kb + kc * 8;
      f32x4 f0 = *(const f32x4*)(src);
      f32x4 f1 = *(const f32x4*)(src + 4);
      bf16x8 bv;
      bv[0] = (__bf16)f0[0]; bv[1] = (__bf16)f0[1];
      bv[2] = (__bf16)f0[2]; bv[3] = (__bf16)f0[3];
      bv[4] = (__bf16)f1[0]; bv[5] = (__bf16)f1[1];
      bv[6] = (__bf16)f1[2]; bv[7] = (__bf16)f1[3];
      *(bf16x8*)(Bs + row * 64 + phys * 8) = bv;
    }
    __syncthreads();
#pragma unroll
    for (int ks = 0; ks < 2; ++ks) {
      bf16x8 af[8], bfr[4];
#pragma unroll
      for (int i = 0; i < 8; ++i) {
        int row = wm + 16 * i + ml;
        int phys = (ks * 4 + kq) ^ (row & 7);
        af[i] = *(const bf16x8*)(As + row * 64 + phys * 8);
      }
#pragma unroll
      for (int j = 0; j < 4; ++j) {
        int row = wn + 16 * j + ml;
        int phys = (ks * 4 + kq) ^ (row & 7);
        bfr[j] = *(const bf16x8*)(Bs + row * 64 + phys * 8);
      }
#pragma unroll
      for (int i = 0; i < 8; ++i)
#pragma unroll
        for (int j = 0; j < 4; ++j)
          acc[i][j] = __builtin_amdgcn_mfma_f32_16x16x32_bf16(af[i], bfr[j], acc[i][j], 0, 0, 0);
    }
  }

  float bv[4];
#pragma unroll
  for (int j = 0; j < 4; ++j) {
    int n = n0 + wn + 16 * j + ml;
    bv[j] = (n < N) ? bias[n] : 0.f;
  }
#pragma unroll
  for (int i = 0; i < 8; ++i) {
    int mrow = m0 + wm + 16 * i + kq * 4;  // C/D: col=lane&15, row=quad*4+reg
#pragma unroll
    for (int j = 0; j < 4; ++j) {
      int n = n0 + wn + 16 * j + ml;
      if (n < N) {
#pragma unroll
        for (int r = 0; r < 4; ++r)
          C[(size_t)(mrow + r) * N + n] = acc[i][j][r] + bv[j];
      }
    }
  }
}

// ---------------------------------------------------------------------------
// Kernel 4: in-place fp32 log-softmax per (row, segment). 2048 blocks x 256.
// ---------------------------------------------------------------------------
__global__ __launch_bounds__(256) void norm_kernel(float* __restrict__ out)
{
  const int b = blockIdx.x;
  const int t = b & 1023;
  const int seg = b >> 10;
  const size_t base = seg == 0 ? (size_t)t * NVG
                               : (size_t)1024 * NVG + (size_t)t * NVS;
  const int len = seg == 0 ? NVG : NVS;
  float* p = out + base;
  const int lane = threadIdx.x & 63;
  const int wv = threadIdx.x >> 6;
  __shared__ float red[4];

  float m = -3.0e38f;
  for (int i = threadIdx.x; i < len; i += 256)
    m = fmaxf(m, p[i]);
#pragma unroll
  for (int off = 32; off; off >>= 1) m = fmaxf(m, __shfl_xor(m, off));
  if (lane == 0) red[wv] = m;
  __syncthreads();
  m = fmaxf(fmaxf(red[0], red[1]), fmaxf(red[2], red[3]));
  __syncthreads();

  float sum = 0.f;
  for (int i = threadIdx.x; i < len; i += 256)
    sum += expf(p[i] - m);
#pragma unroll
  for (int off = 32; off; off >>= 1) sum += __shfl_xor(sum, off);
  if (lane == 0) red[wv] = sum;
  __syncthreads();
  sum = red[0] + red[1] + red[2] + red[3];
  const float lse = m + logf(sum);

  for (int i = threadIdx.x; i < len; i += 256)
    p[i] = p[i] - lse;
}

// ---------------------------------------------------------------------------
extern "C" void kernel_launch(void* const* d_in, const int* in_sizes, int n_in,
                              void* d_out, int out_size, void* d_ws, size_t ws_size,
                              hipStream_t stream) {
  const float* X  = (const float*)d_in[0];
  const float* W1 = (const float*)d_in[1];
  const float* b1 = (const float*)d_in[2];
  const float* W2 = (const float*)d_in[3];
  const float* b2 = (const float*)d_in[4];
  const float* Wg = (const float*)d_in[5];
  const float* bg = (const float*)d_in[6];
  const float* Ws = (const float*)d_in[7];
  const float* bs = (const float*)d_in[8];
  const int* idx = (const int*)d_in[9];
  float* out = (float*)d_out;

  char* ws = (char*)d_ws;
  float* E = (float*)ws;                                         // 4 MB
  __hip_bfloat16* h2s = (__hip_bfloat16*)(ws + (size_t)4194304); // 1 MB
  u64* buf1 = (u64*)(ws + (size_t)5242880);                      // 32 KB
  u64* buf2 = (u64*)(ws + (size_t)5275648);                      // 16 KB

  e_kernel<<<256, 256, 0, stream>>>(X, W1, b1, idx, E);
  rnn_kernel<<<64, 256, 0, stream>>>(W1, W2, b2, E, buf1, buf2, h2s);
  gemm_kernel<<<dim3(4, 391), 256, 0, stream>>>(h2s, Wg, bg, out, NVG);
  gemm_kernel<<<dim3(4, 196), 256, 0, stream>>>(h2s, Ws, bs,
                                                out + (size_t)1024 * NVG, NVS);
  norm_kernel<<<2048, 256, 0, stream>>>(out);
}

// Round 3
// 3549.649 us; speedup vs baseline: 1.4588x; 1.4588x over previous
//
#include <hip/hip_runtime.h>
#include <hip/hip_bf16.h>
#include <stdint.h>

#define T_STEPS 1024
#define NH1 1024
#define NH2 512
#define D_IN 300
#define W1_LD 1324
#define W2_LD 1536
#define NVG 50000
#define NVS 25000

typedef unsigned long long u64;
typedef __bf16 bf16x8 __attribute__((ext_vector_type(8)));
typedef short s16x8 __attribute__((ext_vector_type(8)));
typedef float f32x4 __attribute__((ext_vector_type(4)));

// ---------------------------------------------------------------------------
// Kernel 1: E[t][r] = b1[r] + sum_c W1[r][c] * X[idx[t]][c]   (c < 300)
// ---------------------------------------------------------------------------
__global__ __launch_bounds__(256) void e_kernel(
    const float* __restrict__ X,
    const float* __restrict__ W1,
    const float* __restrict__ b1,
    const int* __restrict__ idx,
    float* __restrict__ E)
{
  __shared__ float Xs[32 * 300];
  const int rb = blockIdx.x & 7;
  const int tb = blockIdx.x >> 3;
  const int r0 = rb * 128;
  const int t0 = tb * 32;

  for (int t = 0; t < 32; ++t) {
    int node = idx[t0 + t];
    for (int c = threadIdx.x; c < 300; c += 256)
      Xs[t * 300 + c] = X[(size_t)node * D_IN + c];
  }
  __syncthreads();

  const int rl = threadIdx.x & 127;
  const int th = threadIdx.x >> 7;
  const int tbase = th * 16;
  const int r = r0 + rl;

  float acc[16];
  const float bias = b1[r];
#pragma unroll
  for (int tt = 0; tt < 16; ++tt) acc[tt] = bias;

  const float* wrow = W1 + (size_t)r * W1_LD;
  for (int c0 = 0; c0 < 300; c0 += 4) {
    float w0 = wrow[c0 + 0];
    float w1 = wrow[c0 + 1];
    float w2 = wrow[c0 + 2];
    float w3 = wrow[c0 + 3];
#pragma unroll
    for (int tt = 0; tt < 16; ++tt) {
      const float* xr = Xs + (tbase + tt) * 300 + c0;
      acc[tt] += w0 * xr[0] + w1 * xr[1] + w2 * xr[2] + w3 * xr[3];
    }
  }
#pragma unroll
  for (int tt = 0; tt < 16; ++tt)
    E[(size_t)(t0 + tbase + tt) * NH1 + r] = acc[tt];
}

// ---------------------------------------------------------------------------
// Kernel 2: persistent RNN, block-cooperative polling.
// 64 blocks x 256 threads. Block b owns h1 rows [16b,16b+16), h2 [8b,8b+8);
// wave w computes h1 rows 16b+4w.. and h2 rows 8b+2w.. with its fp32 weight
// slice in VGPRs (same mapping as wvid=4b+w).
// Polling: wave w polls only ONE quarter of h1 (4 atoms/lane) and of h2
// (2 atoms/lane) -> 6 loads/round, 64 readers/element (was 24/256). Arrived
// quarters go to LDS (double-buffered by step parity, one barrier/step);
// compute reads full h from LDS. Tags embedded in 8B atoms as before; poison
// 0xAAAAAAAA never matches a tag.
// ---------------------------------------------------------------------------
__global__ __launch_bounds__(256, 1) void rnn_kernel(
    const float* __restrict__ W1,
    const float* __restrict__ W2,
    const float* __restrict__ b2,
    const float* __restrict__ E,
    u64* __restrict__ buf1,     // [4][1024]
    u64* __restrict__ buf2,     // [4][512]
    __hip_bfloat16* __restrict__ h2s)   // [T][512]
{
  __shared__ float lds1[2][NH1];
  __shared__ float lds2[2][NH2];

  const int lane = threadIdx.x & 63;
  const int w = threadIdx.x >> 6;                 // wave in block, 0..3
  const int b = blockIdx.x;                       // 0..63
  const int wvid = b * 4 + w;                     // 0..255
  const int r1 = wvid * 4;
  const int r2 = wvid * 2;
  const int q = (w + b) & 3;                      // polled quarter (staggered)

  float w1r[4][16];
#pragma unroll
  for (int i = 0; i < 4; ++i)
#pragma unroll
    for (int j = 0; j < 16; ++j)
      w1r[i][j] = W1[(size_t)(r1 + i) * W1_LD + D_IN + lane + 64 * j];

  float w2r[2][24];
#pragma unroll
  for (int i = 0; i < 2; ++i)
#pragma unroll
    for (int j = 0; j < 24; ++j)
      w2r[i][j] = W2[(size_t)(r2 + i) * W2_LD + lane + 64 * j];

  const float b2a = b2[r2];
  const float b2b = b2[r2 + 1];

  for (int s = 0; s <= T_STEPS; ++s) {
    // Prefetch E for this step's h1 rows (latency overlaps the spin).
    float ev = 0.f;
    if (s < T_STEPS) ev = E[(size_t)s * NH1 + r1 + (lane & 3)];

    // ---- poll my quarter of h1(s) and h2(s-1) ----
    float v1[4] = {0.f, 0.f, 0.f, 0.f};
    float v2[2] = {0.f, 0.f};
    unsigned miss = 0;
    if (s >= 1) miss |= 0xFu;
    if (s >= 2) miss |= 0x30u;
    const u64* p1 = buf1 + (size_t)(s & 3) * NH1 + 256 * q + lane;
    const u64* p2 = buf2 + (size_t)((s - 1) & 3) * NH2 + 128 * q + lane;
    const unsigned tag1 = (unsigned)s;
    const unsigned tag2 = (unsigned)(s - 1);

    while (miss) {
      u64 t1[4], t2[2];
#pragma unroll
      for (int j = 0; j < 4; ++j)
        if (miss & (1u << j))
          t1[j] = __hip_atomic_load(p1 + 64 * j, __ATOMIC_RELAXED,
                                    __HIP_MEMORY_SCOPE_AGENT);
#pragma unroll
      for (int j = 0; j < 2; ++j)
        if (miss & (0x10u << j))
          t2[j] = __hip_atomic_load(p2 + 64 * j, __ATOMIC_RELAXED,
                                    __HIP_MEMORY_SCOPE_AGENT);
#pragma unroll
      for (int j = 0; j < 4; ++j)
        if ((miss & (1u << j)) && (unsigned)(t1[j] >> 32) == tag1) {
          v1[j] = __uint_as_float((unsigned)t1[j]);
          miss &= ~(1u << j);
        }
#pragma unroll
      for (int j = 0; j < 2; ++j)
        if ((miss & (0x10u << j)) && (unsigned)(t2[j] >> 32) == tag2) {
          v2[j] = __uint_as_float((unsigned)t2[j]);
          miss &= ~(0x10u << j);
        }
    }

    // ---- publish quarter to LDS, barrier ----
    const int pb = s & 1;
#pragma unroll
    for (int j = 0; j < 4; ++j) lds1[pb][256 * q + 64 * j + lane] = v1[j];
#pragma unroll
    for (int j = 0; j < 2; ++j) lds2[pb][128 * q + 64 * j + lane] = v2[j];
    __syncthreads();

    // ---- compute from LDS ----
    float a0 = 0.f, a1 = 0.f, a2 = 0.f, a3 = 0.f, a4 = 0.f, a5 = 0.f;
#pragma unroll
    for (int j = 0; j < 16; ++j) {
      float h = lds1[pb][lane + 64 * j];
      a0 += w1r[0][j] * h;
      a1 += w1r[1][j] * h;
      a2 += w1r[2][j] * h;
      a3 += w1r[3][j] * h;
      a4 += w2r[0][j] * h;
      a5 += w2r[1][j] * h;
    }
#pragma unroll
    for (int j = 0; j < 8; ++j) {
      float h = lds2[pb][lane + 64 * j];
      a4 += w2r[0][16 + j] * h;
      a5 += w2r[1][16 + j] * h;
    }

    // h1 critical path first: reduce a0..a3, store.
#pragma unroll
    for (int off = 32; off; off >>= 1) {
      a0 += __shfl_xor(a0, off);
      a1 += __shfl_xor(a1, off);
      a2 += __shfl_xor(a2, off);
      a3 += __shfl_xor(a3, off);
    }
    if (s < T_STEPS && lane < 4) {
      float x = (lane == 0 ? a0 : lane == 1 ? a1 : lane == 2 ? a2 : a3) + ev;
      float h = x > 0.f ? x : 0.01f * x;
      u64 pk = ((u64)(unsigned)(s + 1) << 32) | (u64)__float_as_uint(h);
      __hip_atomic_store(buf1 + (size_t)((s + 1) & 3) * NH1 + r1 + lane, pk,
                         __ATOMIC_RELAXED, __HIP_MEMORY_SCOPE_AGENT);
    }

    // h2 off the critical path.
    if (s >= 1) {
#pragma unroll
      for (int off = 32; off; off >>= 1) {
        a4 += __shfl_xor(a4, off);
        a5 += __shfl_xor(a5, off);
      }
      if (lane >= 4 && lane < 6) {
        int i = lane - 4;
        float x = (i == 0 ? a4 : a5) + (i == 0 ? b2a : b2b);
        float h = x > 0.f ? x : 0.01f * x;
        u64 pk = ((u64)(unsigned)s << 32) | (u64)__float_as_uint(h);
        __hip_atomic_store(buf2 + (size_t)(s & 3) * NH2 + r2 + i, pk,
                           __ATOMIC_RELAXED, __HIP_MEMORY_SCOPE_AGENT);
        h2s[(size_t)(s - 1) * NH2 + r2 + i] = __float2bfloat16(h);
      }
    }
  }
}

// ---------------------------------------------------------------------------
// Kernel 3: C[m][n] = sum_k A[m][k]*B[n][k] + bias[n]  (fp32 logits out).
// A = h2s [1024][512] bf16. B fp32 -> bf16 while staging. 256x128x64 tiles.
// ---------------------------------------------------------------------------
__global__ __launch_bounds__(256, 1) void gemm_kernel(
    const __hip_bfloat16* __restrict__ A,
    const float* __restrict__ B,
    const float* __restrict__ bias,
    float* __restrict__ C,
    int N)
{
  __shared__ short As[256 * 64];
  __shared__ short Bs[128 * 64];
  const int tid = threadIdx.x;
  const int lane = tid & 63;
  const int wv = tid >> 6;
  const int wm = (wv & 1) * 128;
  const int wn = (wv >> 1) * 64;
  const int m0 = blockIdx.x * 256;
  const int n0 = blockIdx.y * 128;
  const int ml = lane & 15;
  const int kq = lane >> 4;

  f32x4 acc[8][4];
#pragma unroll
  for (int i = 0; i < 8; ++i)
#pragma unroll
    for (int j = 0; j < 4; ++j)
      acc[i][j] = (f32x4){0.f, 0.f, 0.f, 0.f};

  for (int kb = 0; kb < 512; kb += 64) {
    __syncthreads();
#pragma unroll
    for (int q = 0; q < 8; ++q) {
      int ch = q * 256 + tid;
      int row = ch >> 3;
      int kc = ch & 7;
      int phys = kc ^ (row & 7);
      s16x8 av = *(const s16x8*)((const short*)A + (size_t)(m0 + row) * 512 + kb + kc * 8);
      *(s16x8*)(As + row * 64 + phys * 8) = av;
    }
#pragma unroll
    for (int q = 0; q < 4; ++q) {
      int ch = q * 256 + tid;
      int row = ch >> 3;
      int kc = ch & 7;
      int phys = kc ^ (row & 7);
      int gr = n0 + row;
      if (gr >= N) gr = N - 1;
      const float* src = B + (size_t)gr * 512 + kb + kc * 8;
      f32x4 f0 = *(const f32x4*)(src);
      f32x4 f1 = *(const f32x4*)(src + 4);
      bf16x8 bv;
      bv[0] = (__bf16)f0[0]; bv[1] = (__bf16)f0[1];
      bv[2] = (__bf16)f0[2]; bv[3] = (__bf16)f0[3];
      bv[4] = (__bf16)f1[0]; bv[5] = (__bf16)f1[1];
      bv[6] = (__bf16)f1[2]; bv[7] = (__bf16)f1[3];
      *(bf16x8*)(Bs + row * 64 + phys * 8) = bv;
    }
    __syncthreads();
#pragma unroll
    for (int ks = 0; ks < 2; ++ks) {
      bf16x8 af[8], bfr[4];
#pragma unroll
      for (int i = 0; i < 8; ++i) {
        int row = wm + 16 * i + ml;
        int phys = (ks * 4 + kq) ^ (row & 7);
        af[i] = *(const bf16x8*)(As + row * 64 + phys * 8);
      }
#pragma unroll
      for (int j = 0; j < 4; ++j) {
        int row = wn + 16 * j + ml;
        int phys = (ks * 4 + kq) ^ (row & 7);
        bfr[j] = *(const bf16x8*)(Bs + row * 64 + phys * 8);
      }
#pragma unroll
      for (int i = 0; i < 8; ++i)
#pragma unroll
        for (int j = 0; j < 4; ++j)
          acc[i][j] = __builtin_amdgcn_mfma_f32_16x16x32_bf16(af[i], bfr[j], acc[i][j], 0, 0, 0);
    }
  }

  float bv[4];
#pragma unroll
  for (int j = 0; j < 4; ++j) {
    int n = n0 + wn + 16 * j + ml;
    bv[j] = (n < N) ? bias[n] : 0.f;
  }
#pragma unroll
  for (int i = 0; i < 8; ++i) {
    int mrow = m0 + wm + 16 * i + kq * 4;
#pragma unroll
    for (int j = 0; j < 4; ++j) {
      int n = n0 + wn + 16 * j + ml;
      if (n < N) {
#pragma unroll
        for (int r = 0; r < 4; ++r)
          C[(size_t)(mrow + r) * N + n] = acc[i][j][r] + bv[j];
      }
    }
  }
}

// ---------------------------------------------------------------------------
// Kernel 4: in-place fp32 log-softmax per (row, segment). 2048 blocks x 256.
// ---------------------------------------------------------------------------
__global__ __launch_bounds__(256) void norm_kernel(float* __restrict__ out)
{
  const int b = blockIdx.x;
  const int t = b & 1023;
  const int seg = b >> 10;
  const size_t base = seg == 0 ? (size_t)t * NVG
                               : (size_t)1024 * NVG + (size_t)t * NVS;
  const int len = seg == 0 ? NVG : NVS;
  float* p = out + base;
  const int lane = threadIdx.x & 63;
  const int wv = threadIdx.x >> 6;
  __shared__ float red[4];

  float m = -3.0e38f;
  for (int i = threadIdx.x; i < len; i += 256)
    m = fmaxf(m, p[i]);
#pragma unroll
  for (int off = 32; off; off >>= 1) m = fmaxf(m, __shfl_xor(m, off));
  if (lane == 0) red[wv] = m;
  __syncthreads();
  m = fmaxf(fmaxf(red[0], red[1]), fmaxf(red[2], red[3]));
  __syncthreads();

  float sum = 0.f;
  for (int i = threadIdx.x; i < len; i += 256)
    sum += expf(p[i] - m);
#pragma unroll
  for (int off = 32; off; off >>= 1) sum += __shfl_xor(sum, off);
  if (lane == 0) red[wv] = sum;
  __syncthreads();
  sum = red[0] + red[1] + red[2] + red[3];
  const float lse = m + logf(sum);

  for (int i = threadIdx.x; i < len; i += 256)
    p[i] = p[i] - lse;
}

// ---------------------------------------------------------------------------
extern "C" void kernel_launch(void* const* d_in, const int* in_sizes, int n_in,
                              void* d_out, int out_size, void* d_ws, size_t ws_size,
                              hipStream_t stream) {
  const float* X  = (const float*)d_in[0];
  const float* W1 = (const float*)d_in[1];
  const float* b1 = (const float*)d_in[2];
  const float* W2 = (const float*)d_in[3];
  const float* b2 = (const float*)d_in[4];
  const float* Wg = (const float*)d_in[5];
  const float* bg = (const float*)d_in[6];
  const float* Ws = (const float*)d_in[7];
  const float* bs = (const float*)d_in[8];
  const int* idx = (const int*)d_in[9];
  float* out = (float*)d_out;

  char* ws = (char*)d_ws;
  float* E = (float*)ws;                                         // 4 MB
  __hip_bfloat16* h2s = (__hip_bfloat16*)(ws + (size_t)4194304); // 1 MB
  u64* buf1 = (u64*)(ws + (size_t)5242880);                      // 32 KB
  u64* buf2 = (u64*)(ws + (size_t)5275648);                      // 16 KB

  e_kernel<<<256, 256, 0, stream>>>(X, W1, b1, idx, E);
  rnn_kernel<<<64, 256, 0, stream>>>(W1, W2, b2, E, buf1, buf2, h2s);
  gemm_kernel<<<dim3(4, 391), 256, 0, stream>>>(h2s, Wg, bg, out, NVG);
  gemm_kernel<<<dim3(4, 196), 256, 0, stream>>>(h2s, Ws, bs,
                                                out + (size_t)1024 * NVG, NVS);
  norm_kernel<<<2048, 256, 0, stream>>>(out);
}